// Round 10
// baseline (184.445 us; speedup 1.0000x reference)
//
#include <hip/hip_runtime.h>
#include <math.h>

#define NB 4
#define HID 4096
#define CKV 512
#define CQ 1536
#define NH 32
#define HD 128
#define RD 64
#define SS 4096
#define SK 4097
#define SKP 4100  // padded scores row stride

#define SCALE_F 0.07216878364870322f  // 1/sqrt(192)

#define NP1 64   // proj1 k-partials
#define NP2 24   // proj2 k-partials
#define NPV 32   // pv key-chunks (128 keys)
#define NUV 16   // uv c-partials
#define NWO 32   // wo k-partials

#define SC_T   64   // scores: keys per tile
#define SC_D4Q 36   // scores: float4s per c-quarter (144 dims)
#define SC_STR 37   // scores: LDS row stride in float4 (148 floats -> 4-way max)

// workspace offsets (floats). NO memsets — every cell written before read.
enum : int {
  WS_QABS  = 0,                      // [NB][NH][CKV] pre-scaled
  WS_QROPE = WS_QABS + NB*NH*CKV,    // [NB][NH][RD]  pre-scaled
  WS_KROPE = WS_QROPE + NB*NH*RD,    // [NB][RD]
  WS_CKV   = WS_KROPE + NB*RD,       // [NB][CKV]
  WS_CQ    = WS_CKV + NB*CKV,        // [NB][CQ]
  WS_OLAT  = WS_CQ + NB*CQ,          // [NB][NH][CKV]
  WS_ATTN  = WS_OLAT + NB*NH*CKV,    // [NB][HID]
  WS_SCA   = WS_ATTN + NB*HID,       // [NB][NH][SKP] c-quarter 0 -> probs
  WS_SCB   = WS_SCA + NB*NH*SKP,     // c-quarter 1
  WS_SCC   = WS_SCB + NB*NH*SKP,     // c-quarter 2
  WS_SCD   = WS_SCC + NB*NH*SKP,     // c-quarter 3 (incl rope)
  WS_R1    = WS_SCD + NB*NH*SKP,     // lifetime-shared partials region
  WS_TOTAL = WS_R1 + NPV*NB*NH*CKV
};
#define WS_P1     WS_R1
#define WS_P2     WS_R1
#define WS_OPART  WS_R1
#define WS_UVPART WS_R1
#define WS_WOPART WS_R1

__device__ inline void fma4(float4& a, float s, const float4& v) {
  a.x += s*v.x; a.y += s*v.y; a.z += s*v.z; a.w += s*v.w;
}
__device__ inline float dot4(const float4& a, const float4& b) {
  return a.x*b.x + a.y*b.y + a.z*b.z + a.w*b.w;
}

// ---------------- K1: hidden -> P1 partials (block k-split, LDS reduce) -----
__global__ __launch_bounds__(256)
void k_proj1(const float* __restrict__ hidden,
             const float* __restrict__ Wdkv,
             const float* __restrict__ Wdq,
             const float* __restrict__ Wkr,
             float* __restrict__ ws) {
  __shared__ float4 red_s[4][NB][64];
  const int lane = threadIdx.x & 63, ksub = threadIdx.x >> 6;
  const int col4 = blockIdx.x * 64 + lane;
  const int k0 = blockIdx.y * 64 + ksub * 16;
  const bool valid = col4 < 528;
  float4 acc[NB] = {};
  if (valid) {
    const float* W; int C4, wcol4;
    if (col4 < 128)      { W = Wdkv; C4 = 128; wcol4 = col4; }
    else if (col4 < 512) { W = Wdq;  C4 = 384; wcol4 = col4 - 128; }
    else                 { W = Wkr;  C4 = 16;  wcol4 = col4 - 512; }
    const float4* wp = (const float4*)W + (size_t)k0 * C4 + wcol4;
    #pragma unroll
    for (int i = 0; i < 16; ++i) {
      float4 w4 = wp[(size_t)i * C4];
      #pragma unroll
      for (int b = 0; b < NB; ++b) fma4(acc[b], hidden[b*HID + k0 + i], w4);
    }
  }
  #pragma unroll
  for (int b = 0; b < NB; ++b) red_s[ksub][b][lane] = acc[b];
  __syncthreads();
  if (ksub == 0 && valid) {
    #pragma unroll
    for (int b = 0; b < NB; ++b) {
      float4 s = red_s[0][b][lane];
      #pragma unroll
      for (int j = 1; j < 4; ++j) {
        float4 v = red_s[j][b][lane];
        s.x += v.x; s.y += v.y; s.z += v.z; s.w += v.w;
      }
      *(float4*)(ws + WS_P1 + ((size_t)(blockIdx.y*NB + b)*528 + col4)*4) = s;
    }
  }
}

// ---------------- R1: reduce P1 -> c_KV, c_Q; k_R RoPE; cache row SS --------
__global__ __launch_bounds__(256)
void k_reduce1(float* __restrict__ ws,
               float* __restrict__ out_ckv,
               float* __restrict__ out_kr) {
  const int w = blockIdx.x * 256 + threadIdx.x;  // < 2112
  if (w >= 528*NB) return;
  const int b = w / 528, col4 = w % 528;
  float4 s = {};
  #pragma unroll 8
  for (int p = 0; p < NP1; ++p) {
    float4 v = *(const float4*)(ws + WS_P1 + ((size_t)(p*NB + b)*528 + col4)*4);
    s.x += v.x; s.y += v.y; s.z += v.z; s.w += v.w;
  }
  if (col4 < 128) {
    *(float4*)(ws + WS_CKV + b*CKV + col4*4) = s;
    *(float4*)(out_ckv + (size_t)b*SK*CKV + (size_t)SS*CKV + col4*4) = s;
  } else if (col4 < 512) {
    *(float4*)(ws + WS_CQ + b*CQ + (col4 - 128)*4) = s;
  } else {
    const int c0 = (col4 - 512) * 4;
    const double LN1E4 = 9.210340371976184;
    int i0 = c0 >> 1;
    double a0 = 4096.0 * exp(-(double)i0 / 32.0 * LN1E4);
    double a1 = 4096.0 * exp(-(double)(i0 + 1) / 32.0 * LN1E4);
    float c0f = (float)cos(a0), s0f = (float)sin(a0);
    float c1f = (float)cos(a1), s1f = (float)sin(a1);
    float4 o;
    o.x = s.x*c0f - s.y*s0f;  o.y = s.x*s0f + s.y*c0f;
    o.z = s.z*c1f - s.w*s1f;  o.w = s.z*s1f + s.w*c1f;
    *(float4*)(ws + WS_KROPE + b*RD + c0) = o;
    *(float4*)(out_kr + (size_t)b*SK*RD + (size_t)SS*RD + c0) = o;
  }
}

// ---------------- K2: c_Q -> P2 partials (block k-split, LDS reduce) --------
__global__ __launch_bounds__(256)
void k_proj2(const float* __restrict__ Wuq,
             const float* __restrict__ Wqr,
             float* __restrict__ ws) {
  __shared__ float4 red_s[4][NB][64];
  const int lane = threadIdx.x & 63, ksub = threadIdx.x >> 6;
  const int col4 = blockIdx.x * 64 + lane;   // < 1536
  const int k0 = blockIdx.y * 64 + ksub * 16;
  const float* W; int C4, wcol4;
  if (col4 < 1024) { W = Wuq; C4 = 1024; wcol4 = col4; }
  else             { W = Wqr; C4 = 512;  wcol4 = col4 - 1024; }
  const float4* wp = (const float4*)W + (size_t)k0 * C4 + wcol4;
  const float* act = ws + WS_CQ;
  float4 acc[NB] = {};
  #pragma unroll
  for (int i = 0; i < 16; ++i) {
    float4 w4 = wp[(size_t)i * C4];
    #pragma unroll
    for (int b = 0; b < NB; ++b) fma4(acc[b], act[b*CQ + k0 + i], w4);
  }
  #pragma unroll
  for (int b = 0; b < NB; ++b) red_s[ksub][b][lane] = acc[b];
  __syncthreads();
  if (ksub == 0) {
    #pragma unroll
    for (int b = 0; b < NB; ++b) {
      float4 s = red_s[0][b][lane];
      #pragma unroll
      for (int j = 1; j < 4; ++j) {
        float4 v = red_s[j][b][lane];
        s.x += v.x; s.y += v.y; s.z += v.z; s.w += v.w;
      }
      *(float4*)(ws + WS_P2 + (size_t)(blockIdx.y*NB + b)*6144 + col4*4) = s;
    }
  }
}

// -------- K3: q_abs = q_C @ W_UK^T (×SCALE), P2-reduce fused; q_R RoPE -------
__global__ __launch_bounds__(256)
void k_absorb_rope(const float* __restrict__ Wuk,
                   float* __restrict__ ws) {
  const int bid = blockIdx.x, tid = threadIdx.x;
  if (bid < 256) {
    const int h = bid >> 3, cq = bid & 7;
    __shared__ float qc_s[NB][HD];
    __shared__ float part_s[NB][256];
    for (int e = tid; e < NB*HD; e += 256) {
      int b = e >> 7, d = e & 127;
      float v = 0.f;
      #pragma unroll
      for (int p = 0; p < NP2; ++p)
        v += ws[WS_P2 + (size_t)(p*NB + b)*6144 + h*HD + d];
      qc_s[b][d] = v;
    }
    __syncthreads();
    const int c = cq*64 + (tid & 63);
    const int dg = tid >> 6;
    const float4* wrow = (const float4*)(Wuk + (size_t)c*(NH*HD) + h*HD + dg*32);
    float acc[NB] = {0,0,0,0};
    #pragma unroll
    for (int d4 = 0; d4 < 8; ++d4) {
      float4 w4 = wrow[d4];
      #pragma unroll
      for (int b = 0; b < NB; ++b)
        acc[b] += dot4(w4, *(const float4*)&qc_s[b][dg*32 + d4*4]);
    }
    #pragma unroll
    for (int b = 0; b < NB; ++b) part_s[b][tid] = acc[b];
    __syncthreads();
    if (tid < 64) {
      #pragma unroll
      for (int b = 0; b < NB; ++b) {
        float v = part_s[b][tid] + part_s[b][tid+64] + part_s[b][tid+128] + part_s[b][tid+192];
        ws[WS_QABS + (size_t)(b*NH + h)*CKV + cq*64 + tid] = v * SCALE_F;
      }
    }
  } else {
    const int b = bid - 256;
    const double LN1E4 = 9.210340371976184;
    for (int pid = tid; pid < NH*32; pid += 256) {
      int h = pid >> 5, i = pid & 31;
      float x1 = 0.f, x2 = 0.f;
      #pragma unroll
      for (int p = 0; p < NP2; ++p) {
        const float* base = ws + WS_P2 + (size_t)(p*NB + b)*6144 + 4096 + h*RD + 2*i;
        x1 += base[0]; x2 += base[1];
      }
      double ang = 4096.0 * exp(-(double)i / 32.0 * LN1E4);
      float cs = (float)cos(ang), sn = (float)sin(ang);
      ws[WS_QROPE + (b*NH + h)*RD + 2*i]     = (x1*cs - x2*sn) * SCALE_F;
      ws[WS_QROPE + (b*NH + h)*RD + 2*i + 1] = (x1*sn + x2*cs) * SCALE_F;
    }
  }
}

// ---------------- K4: scores v5 — reg-tiled 4h×2k, q from L2, fused copy ----
// block: 64 keys × 32 heads × 144-dim c-quarter; grid (65, 4, 4) = 1040.
// Only kv in LDS (37.9 KB -> 4 blocks/CU); q streamed from L2 (1 MB resident).
// LDS reads: 2 b128/iter (was 5+). Staged tile also written to out_ckv/out_kr
// (each (row,dim) staged exactly once across grid) — replaces k_copy.
__global__ __launch_bounds__(256)
void k_scores(const float* __restrict__ kv_cache,
              const float* __restrict__ kr_cache,
              float* __restrict__ ws,
              float* __restrict__ out_ckv,
              float* __restrict__ out_kr) {
  __shared__ float4 kv_s[SC_T * SC_STR];
  const int tid = threadIdx.x;
  const int b  = blockIdx.z;
  const int cs = blockIdx.y;
  const int k0 = blockIdx.x * SC_T;
  // ---- stage kv tile (4 threads/row, 9 f4 each) + fused cache-copy write
  {
    const int row = tid >> 2;
    const int c4a = (tid & 3) * 9;
    const int k = k0 + row;
    const int prow = ((row & 1) << 5) | (row >> 1);   // interleaved physical row
    const float4* kvr = nullptr; const float4* krr = nullptr;
    if (k < SS)       { kvr = (const float4*)(kv_cache + ((size_t)b*SS + k)*CKV);
                        krr = (const float4*)(kr_cache + ((size_t)b*SS + k)*RD); }
    else if (k == SS) { kvr = (const float4*)(ws + WS_CKV + b*CKV);
                        krr = (const float4*)(ws + WS_KROPE + b*RD); }
    float4* dck = (k < SS) ? (float4*)(out_ckv + ((size_t)b*SK + k)*CKV) : nullptr;
    float4* dkr = (k < SS) ? (float4*)(out_kr + ((size_t)b*SK + k)*RD) : nullptr;
    #pragma unroll
    for (int i = 0; i < 9; ++i) {
      int c4 = c4a + i;
      int g4 = cs * SC_D4Q + c4;
      float4 v = make_float4(0.f, 0.f, 0.f, 0.f);
      if (kvr) v = (g4 < 128) ? kvr[g4] : krr[g4 - 128];
      kv_s[prow * SC_STR + c4] = v;
      if (dck) { if (g4 < 128) dck[g4] = v; else dkr[g4 - 128] = v; }
    }
  }
  __syncthreads();
  // ---- compute: thread = (hg=tid>>5 -> heads hg*4+i) × (kg=tid&31 -> keys 2kg+j)
  const int hg = tid >> 5, kg = tid & 31;
  const float4* qa[4]; const float4* qr[4];
  #pragma unroll
  for (int i = 0; i < 4; ++i) {
    int h = hg*4 + i;
    qa[i] = (const float4*)(ws + WS_QABS + (size_t)(b*NH + h)*CKV);
    qr[i] = (const float4*)(ws + WS_QROPE + (size_t)(b*NH + h)*RD);
  }
  const float4* kvrow0 = &kv_s[kg * SC_STR];           // logical row 2kg
  const float4* kvrow1 = &kv_s[(32 + kg) * SC_STR];    // logical row 2kg+1
  float acc[4][2] = {};
  if (cs < 3) {
    const int g0 = cs * SC_D4Q;
    #pragma unroll 4
    for (int c4 = 0; c4 < SC_D4Q; ++c4) {
      float4 kv0 = kvrow0[c4], kv1 = kvrow1[c4];
      #pragma unroll
      for (int i = 0; i < 4; ++i) {
        float4 q = qa[i][g0 + c4];
        acc[i][0] += dot4(q, kv0);
        acc[i][1] += dot4(q, kv1);
      }
    }
  } else {
    #pragma unroll 4
    for (int c4 = 0; c4 < 20; ++c4) {      // latent dims 432..511
      float4 kv0 = kvrow0[c4], kv1 = kvrow1[c4];
      #pragma unroll
      for (int i = 0; i < 4; ++i) {
        float4 q = qa[i][108 + c4];
        acc[i][0] += dot4(q, kv0);
        acc[i][1] += dot4(q, kv1);
      }
    }
    #pragma unroll 4
    for (int c4 = 20; c4 < 36; ++c4) {     // rope dims 0..63
      float4 kv0 = kvrow0[c4], kv1 = kvrow1[c4];
      #pragma unroll
      for (int i = 0; i < 4; ++i) {
        float4 q = qr[i][c4 - 20];
        acc[i][0] += dot4(q, kv0);
        acc[i][1] += dot4(q, kv1);
      }
    }
  }
  float* sbuf = ws + (cs == 0 ? WS_SCA : cs == 1 ? WS_SCB : cs == 2 ? WS_SCC : WS_SCD);
  const int ka = k0 + 2*kg, kb = ka + 1;
  #pragma unroll
  for (int i = 0; i < 4; ++i) {
    float* srow = sbuf + (size_t)(b*NH + hg*4 + i)*SKP;
    if (ka < SK) srow[ka] = acc[i][0];
    if (kb < SK) srow[kb] = acc[i][1];
  }
}

// ---------------- K5: softmax(SCA+SCB+SCC+SCD+mask) -> probs in SCA ---------
__global__ __launch_bounds__(256)
void k_softmax(const float* __restrict__ mask, float* __restrict__ ws) {
  __shared__ float red[256];
  const int tid = threadIdx.x;
  const int b = blockIdx.x >> 5;
  float* sa = ws + WS_SCA + (size_t)blockIdx.x * SKP;
  const float* sb = ws + WS_SCB + (size_t)blockIdx.x * SKP;
  const float* sc = ws + WS_SCC + (size_t)blockIdx.x * SKP;
  const float* sd = ws + WS_SCD + (size_t)blockIdx.x * SKP;
  const float* mrow = mask + (size_t)b * SK;
  float v[17];
  float m = -INFINITY;
  #pragma unroll
  for (int r = 0; r < 17; ++r) {
    int k = tid + r*256;
    v[r] = (k < SK) ? (sa[k] + sb[k] + sc[k] + sd[k] + mrow[k] * (-1e9f)) : -INFINITY;
    m = fmaxf(m, v[r]);
  }
  red[tid] = m; __syncthreads();
  for (int st = 128; st > 0; st >>= 1) {
    if (tid < st) red[tid] = fmaxf(red[tid], red[tid+st]);
    __syncthreads();
  }
  m = red[0]; __syncthreads();
  float e[17];
  float l = 0.f;
  #pragma unroll
  for (int r = 0; r < 17; ++r) {
    int k = tid + r*256;
    e[r] = (k < SK) ? __expf(v[r] - m) : 0.f;
    l += e[r];
  }
  red[tid] = l; __syncthreads();
  for (int st = 128; st > 0; st >>= 1) {
    if (tid < st) red[tid] += red[tid+st];
    __syncthreads();
  }
  float inv = 1.f / red[0];
  #pragma unroll
  for (int r = 0; r < 17; ++r) {
    int k = tid + r*256;
    if (k < SK) sa[k] = e[r] * inv;
  }
}

// ---------------- K6: o_latent partials — LDS-staged probs ------------------
__global__ __launch_bounds__(256)
void k_pv(const float* __restrict__ kv_cache, float* __restrict__ ws) {
  __shared__ float p_s[32][132];
  const int tid = threadIdx.x;
  const int c4 = tid & 15, hg = tid >> 4;
  const int b  = blockIdx.z;
  const int c  = blockIdx.y * 64 + c4 * 4;
  const int k0 = blockIdx.x * 128;
  #pragma unroll
  for (int j = 0; j < 4; ++j) {
    int e = tid + j*256;
    int h = e >> 5, k4 = e & 31;
    *(float4*)&p_s[h][k4*4] =
        *(const float4*)(ws + WS_SCA + (size_t)(b*NH + h)*SKP + k0 + k4*4);
  }
  __syncthreads();
  const float* kvp = kv_cache + ((size_t)b*SS + k0)*CKV + c;
  float4 acc0 = {}, acc1 = {};
  #pragma unroll 4
  for (int kk = 0; kk < 128; kk += 4) {
    float4 kv4[4];
    #pragma unroll
    for (int j = 0; j < 4; ++j)
      kv4[j] = *(const float4*)(kvp + (size_t)(kk + j)*CKV);
    float4 p4a = *(const float4*)&p_s[hg][kk];
    float4 p4b = *(const float4*)&p_s[hg + 16][kk];
    fma4(acc0, p4a.x, kv4[0]); fma4(acc1, p4b.x, kv4[0]);
    fma4(acc0, p4a.y, kv4[1]); fma4(acc1, p4b.y, kv4[1]);
    fma4(acc0, p4a.z, kv4[2]); fma4(acc1, p4b.z, kv4[2]);
    fma4(acc0, p4a.w, kv4[3]); fma4(acc1, p4b.w, kv4[3]);
  }
  if (blockIdx.x == NPV - 1) {
    float4 kv = *(const float4*)(ws + WS_CKV + b*CKV + c);
    float pa = ws[WS_SCA + (size_t)(b*NH + hg)*SKP + SS];
    float pb = ws[WS_SCA + (size_t)(b*NH + hg + 16)*SKP + SS];
    fma4(acc0, pa, kv);
    fma4(acc1, pb, kv);
  }
  *(float4*)(ws + WS_OPART + (((size_t)blockIdx.x*NB + b)*NH + hg)*CKV + c) = acc0;
  *(float4*)(ws + WS_OPART + (((size_t)blockIdx.x*NB + b)*NH + hg + 16)*CKV + c) = acc1;
}

// ---------------- R3: OLAT = sum_p OPART[p] ----------------------------------
__global__ __launch_bounds__(256)
void k_reduce3(float* __restrict__ ws) {
  const int idx = blockIdx.x * 256 + threadIdx.x;
  float4 s = {};
  #pragma unroll 8
  for (int p = 0; p < NPV; ++p) {
    float4 v = *(const float4*)(ws + WS_OPART + (size_t)p*(NB*NH*CKV) + (size_t)idx*4);
    s.x += v.x; s.y += v.y; s.z += v.z; s.w += v.w;
  }
  *(float4*)(ws + WS_OLAT + (size_t)idx*4) = s;
}

// ---------------- K7: UVPART = o_latent @ W_UV (block c-split) --------------
__global__ __launch_bounds__(256)
void k_uv(const float* __restrict__ Wuv, float* __restrict__ ws) {
  __shared__ float4 red_s[4][NB][64];
  const int lane = threadIdx.x & 63, csub = threadIdx.x >> 6;
  const int col4 = blockIdx.x * 64 + lane;
  const int h = col4 >> 5;
  const int k0 = blockIdx.y * 32 + csub * 8;
  const float4* wp = (const float4*)Wuv + (size_t)k0 * 1024 + col4;
  float4 acc[NB] = {};
  #pragma unroll
  for (int i = 0; i < 8; ++i) {
    float4 w4 = wp[(size_t)i * 1024];
    #pragma unroll
    for (int b = 0; b < NB; ++b)
      fma4(acc[b], ws[WS_OLAT + (size_t)(b*NH + h)*CKV + k0 + i], w4);
  }
  #pragma unroll
  for (int b = 0; b < NB; ++b) red_s[csub][b][lane] = acc[b];
  __syncthreads();
  if (csub == 0) {
    #pragma unroll
    for (int b = 0; b < NB; ++b) {
      float4 s = red_s[0][b][lane];
      #pragma unroll
      for (int j = 1; j < 4; ++j) {
        float4 v = red_s[j][b][lane];
        s.x += v.x; s.y += v.y; s.z += v.z; s.w += v.w;
      }
      *(float4*)(ws + WS_UVPART + (size_t)(blockIdx.y*NB + b)*HID + col4*4) = s;
    }
  }
}

// ---------------- R4: ATTN = sum_p UVPART[p] ---------------------------------
__global__ __launch_bounds__(256)
void k_reduce4(float* __restrict__ ws) {
  const int idx = blockIdx.x * 256 + threadIdx.x;
  float4 s = {};
  #pragma unroll
  for (int p = 0; p < NUV; ++p) {
    float4 v = *(const float4*)(ws + WS_UVPART + (size_t)p*(NB*HID) + (size_t)idx*4);
    s.x += v.x; s.y += v.y; s.z += v.z; s.w += v.w;
  }
  *(float4*)(ws + WS_ATTN + (size_t)idx*4) = s;
}

// ---------------- K8: WOPART = attn @ W_O (block k-split) --------------------
__global__ __launch_bounds__(256)
void k_wo(const float* __restrict__ Wo, const float* __restrict__ ws,
          float* __restrict__ wsp) {
  __shared__ float4 red_s[4][NB][64];
  const int lane = threadIdx.x & 63, ksub = threadIdx.x >> 6;
  const int col4 = blockIdx.x * 64 + lane;
  const int k0 = blockIdx.y * 128 + ksub * 32;
  const float4* wp = (const float4*)Wo + (size_t)k0 * 1024 + col4;
  float4 acc[NB] = {};
  #pragma unroll 8
  for (int i = 0; i < 32; ++i) {
    float4 w4 = wp[(size_t)i * 1024];
    #pragma unroll
    for (int b = 0; b < NB; ++b)
      fma4(acc[b], ws[WS_ATTN + b*HID + k0 + i], w4);
  }
  #pragma unroll
  for (int b = 0; b < NB; ++b) red_s[ksub][b][lane] = acc[b];
  __syncthreads();
  if (ksub == 0) {
    #pragma unroll
    for (int b = 0; b < NB; ++b) {
      float4 s = red_s[0][b][lane];
      #pragma unroll
      for (int j = 1; j < 4; ++j) {
        float4 v = red_s[j][b][lane];
        s.x += v.x; s.y += v.y; s.z += v.z; s.w += v.w;
      }
      *(float4*)(wsp + WS_WOPART + (size_t)(blockIdx.y*NB + b)*HID + col4*4) = s;
    }
  }
}

// ---------------- R5: out = sum_p WOPART[p] ----------------------------------
__global__ __launch_bounds__(256)
void k_reduce5(const float* __restrict__ ws, float* __restrict__ out) {
  const int idx = blockIdx.x * 256 + threadIdx.x;
  float4 s = {};
  #pragma unroll 8
  for (int p = 0; p < NWO; ++p) {
    float4 v = *(const float4*)(ws + WS_WOPART + (size_t)p*(NB*HID) + (size_t)idx*4);
    s.x += v.x; s.y += v.y; s.z += v.z; s.w += v.w;
  }
  *(float4*)(out + (size_t)idx*4) = s;
}

extern "C" void kernel_launch(void* const* d_in, const int* in_sizes, int n_in,
                              void* d_out, int out_size, void* d_ws, size_t ws_size,
                              hipStream_t stream) {
  (void)in_sizes; (void)n_in; (void)out_size; (void)ws_size;
  const float* hidden = (const float*)d_in[0];
  const float* mask   = (const float*)d_in[1];
  const float* ckv_c  = (const float*)d_in[2];
  const float* kr_c   = (const float*)d_in[3];
  const float* Wdkv   = (const float*)d_in[4];
  const float* Wuk    = (const float*)d_in[5];
  const float* Wuv    = (const float*)d_in[6];
  const float* Wdq    = (const float*)d_in[7];
  const float* Wuq    = (const float*)d_in[8];
  const float* Wqr    = (const float*)d_in[9];
  const float* Wkr    = (const float*)d_in[10];
  const float* Wo     = (const float*)d_in[11];
  float* out = (float*)d_out;
  float* ws  = (float*)d_ws;
  float* out_ckv = out + NB*HID;
  float* out_kr  = out + NB*HID + (size_t)NB*SK*CKV;

  k_proj1<<<dim3(9, NP1), 256, 0, stream>>>(hidden, Wdkv, Wdq, Wkr, ws);
  k_reduce1<<<9, 256, 0, stream>>>(ws, out_ckv, out_kr);
  k_proj2<<<dim3(24, NP2), 256, 0, stream>>>(Wuq, Wqr, ws);
  k_absorb_rope<<<260, 256, 0, stream>>>(Wuk, ws);
  k_scores<<<dim3(65, 4, 4), 256, 0, stream>>>(ckv_c, kr_c, ws, out_ckv, out_kr);
  k_softmax<<<NB*NH, 256, 0, stream>>>(mask, ws);
  k_pv<<<dim3(NPV, 8, 4), 256, 0, stream>>>(ckv_c, ws);
  k_reduce3<<<64, 256, 0, stream>>>(ws);
  k_uv<<<dim3(16, NUV), 256, 0, stream>>>(Wuv, ws);
  k_reduce4<<<16, 256, 0, stream>>>(ws);
  k_wo<<<dim3(16, NWO), 256, 0, stream>>>(Wo, ws, ws);
  k_reduce5<<<16, 256, 0, stream>>>(ws, out);
}

// Round 11
// 158.968 us; speedup vs baseline: 1.1603x; 1.1603x over previous
//
#include <hip/hip_runtime.h>
#include <math.h>

#define NB 4
#define HID 4096
#define CKV 512
#define CQ 1536
#define NH 32
#define HD 128
#define RD 64
#define SS 4096
#define SK 4097
#define SKP 4100  // padded scores row stride

#define SCALE_F 0.07216878364870322f  // 1/sqrt(192)

#define NP1 64   // proj1 k-partials
#define NP2 24   // proj2 k-partials
#define NPV 32   // pv key-chunks (128 keys)
#define NUV 16   // uv c-partials
#define NWO 32   // wo k-partials

#define SC_T   64   // scores: keys per tile
#define SC_D4Q 36   // scores: float4s per c-quarter (144 dims)
#define SC_STR 37   // scores: LDS row stride in float4

// workspace offsets (floats). NO memsets — every cell written before read.
enum : int {
  WS_QABS  = 0,                      // [NB][NH][CKV] pre-scaled
  WS_QROPE = WS_QABS + NB*NH*CKV,    // [NB][NH][RD]  pre-scaled
  WS_KROPE = WS_QROPE + NB*NH*RD,    // [NB][RD]
  WS_CKV   = WS_KROPE + NB*RD,       // [NB][CKV]
  WS_CQ    = WS_CKV + NB*CKV,        // [NB][CQ]
  WS_OLAT  = WS_CQ + NB*CQ,          // [NB][NH][CKV]
  WS_ATTN  = WS_OLAT + NB*NH*CKV,    // [NB][HID]
  WS_SCA   = WS_ATTN + NB*HID,       // [NB][NH][SKP] c-quarter 0 -> probs
  WS_SCB   = WS_SCA + NB*NH*SKP,     // c-quarter 1
  WS_SCC   = WS_SCB + NB*NH*SKP,     // c-quarter 2
  WS_SCD   = WS_SCC + NB*NH*SKP,     // c-quarter 3 (incl rope)
  WS_R1    = WS_SCD + NB*NH*SKP,     // lifetime-shared partials region
  WS_TOTAL = WS_R1 + NPV*NB*NH*CKV
};
#define WS_P1     WS_R1
#define WS_P2     WS_R1
#define WS_OPART  WS_R1
#define WS_UVPART WS_R1
#define WS_WOPART WS_R1

__device__ inline void fma4(float4& a, float s, const float4& v) {
  a.x += s*v.x; a.y += s*v.y; a.z += s*v.z; a.w += s*v.w;
}
__device__ inline float dot4(const float4& a, const float4& b) {
  return a.x*b.x + a.y*b.y + a.z*b.z + a.w*b.w;
}

// ---------------- K1: hidden -> P1 partials (block k-split, LDS reduce) -----
__global__ __launch_bounds__(256)
void k_proj1(const float* __restrict__ hidden,
             const float* __restrict__ Wdkv,
             const float* __restrict__ Wdq,
             const float* __restrict__ Wkr,
             float* __restrict__ ws) {
  __shared__ float4 red_s[4][NB][64];
  const int lane = threadIdx.x & 63, ksub = threadIdx.x >> 6;
  const int col4 = blockIdx.x * 64 + lane;
  const int k0 = blockIdx.y * 64 + ksub * 16;
  const bool valid = col4 < 528;
  float4 acc[NB] = {};
  if (valid) {
    const float* W; int C4, wcol4;
    if (col4 < 128)      { W = Wdkv; C4 = 128; wcol4 = col4; }
    else if (col4 < 512) { W = Wdq;  C4 = 384; wcol4 = col4 - 128; }
    else                 { W = Wkr;  C4 = 16;  wcol4 = col4 - 512; }
    const float4* wp = (const float4*)W + (size_t)k0 * C4 + wcol4;
    #pragma unroll
    for (int i = 0; i < 16; ++i) {
      float4 w4 = wp[(size_t)i * C4];
      #pragma unroll
      for (int b = 0; b < NB; ++b) fma4(acc[b], hidden[b*HID + k0 + i], w4);
    }
  }
  #pragma unroll
  for (int b = 0; b < NB; ++b) red_s[ksub][b][lane] = acc[b];
  __syncthreads();
  if (ksub == 0 && valid) {
    #pragma unroll
    for (int b = 0; b < NB; ++b) {
      float4 s = red_s[0][b][lane];
      #pragma unroll
      for (int j = 1; j < 4; ++j) {
        float4 v = red_s[j][b][lane];
        s.x += v.x; s.y += v.y; s.z += v.z; s.w += v.w;
      }
      *(float4*)(ws + WS_P1 + ((size_t)(blockIdx.y*NB + b)*528 + col4)*4) = s;
    }
  }
}

// ---------------- R1: reduce P1 -> c_KV, c_Q; k_R RoPE; cache row SS --------
__global__ __launch_bounds__(256)
void k_reduce1(float* __restrict__ ws,
               float* __restrict__ out_ckv,
               float* __restrict__ out_kr) {
  const int w = blockIdx.x * 256 + threadIdx.x;  // < 2112
  if (w >= 528*NB) return;
  const int b = w / 528, col4 = w % 528;
  float4 s = {};
  #pragma unroll 8
  for (int p = 0; p < NP1; ++p) {
    float4 v = *(const float4*)(ws + WS_P1 + ((size_t)(p*NB + b)*528 + col4)*4);
    s.x += v.x; s.y += v.y; s.z += v.z; s.w += v.w;
  }
  if (col4 < 128) {
    *(float4*)(ws + WS_CKV + b*CKV + col4*4) = s;
    *(float4*)(out_ckv + (size_t)b*SK*CKV + (size_t)SS*CKV + col4*4) = s;
  } else if (col4 < 512) {
    *(float4*)(ws + WS_CQ + b*CQ + (col4 - 128)*4) = s;
  } else {
    const int c0 = (col4 - 512) * 4;
    const double LN1E4 = 9.210340371976184;
    int i0 = c0 >> 1;
    double a0 = 4096.0 * exp(-(double)i0 / 32.0 * LN1E4);
    double a1 = 4096.0 * exp(-(double)(i0 + 1) / 32.0 * LN1E4);
    float c0f = (float)cos(a0), s0f = (float)sin(a0);
    float c1f = (float)cos(a1), s1f = (float)sin(a1);
    float4 o;
    o.x = s.x*c0f - s.y*s0f;  o.y = s.x*s0f + s.y*c0f;
    o.z = s.z*c1f - s.w*s1f;  o.w = s.z*s1f + s.w*c1f;
    *(float4*)(ws + WS_KROPE + b*RD + c0) = o;
    *(float4*)(out_kr + (size_t)b*SK*RD + (size_t)SS*RD + c0) = o;
  }
}

// ---------------- K2: c_Q -> P2 partials (block k-split, LDS reduce) --------
__global__ __launch_bounds__(256)
void k_proj2(const float* __restrict__ Wuq,
             const float* __restrict__ Wqr,
             float* __restrict__ ws) {
  __shared__ float4 red_s[4][NB][64];
  const int lane = threadIdx.x & 63, ksub = threadIdx.x >> 6;
  const int col4 = blockIdx.x * 64 + lane;   // < 1536
  const int k0 = blockIdx.y * 64 + ksub * 16;
  const float* W; int C4, wcol4;
  if (col4 < 1024) { W = Wuq; C4 = 1024; wcol4 = col4; }
  else             { W = Wqr; C4 = 512;  wcol4 = col4 - 1024; }
  const float4* wp = (const float4*)W + (size_t)k0 * C4 + wcol4;
  const float* act = ws + WS_CQ;
  float4 acc[NB] = {};
  #pragma unroll
  for (int i = 0; i < 16; ++i) {
    float4 w4 = wp[(size_t)i * C4];
    #pragma unroll
    for (int b = 0; b < NB; ++b) fma4(acc[b], act[b*CQ + k0 + i], w4);
  }
  #pragma unroll
  for (int b = 0; b < NB; ++b) red_s[ksub][b][lane] = acc[b];
  __syncthreads();
  if (ksub == 0) {
    #pragma unroll
    for (int b = 0; b < NB; ++b) {
      float4 s = red_s[0][b][lane];
      #pragma unroll
      for (int j = 1; j < 4; ++j) {
        float4 v = red_s[j][b][lane];
        s.x += v.x; s.y += v.y; s.z += v.z; s.w += v.w;
      }
      *(float4*)(ws + WS_P2 + (size_t)(blockIdx.y*NB + b)*6144 + col4*4) = s;
    }
  }
}

// -------- K3: q_abs = q_C @ W_UK^T (×SCALE), P2-reduce fused; q_R RoPE -------
__global__ __launch_bounds__(256)
void k_absorb_rope(const float* __restrict__ Wuk,
                   float* __restrict__ ws) {
  const int bid = blockIdx.x, tid = threadIdx.x;
  if (bid < 256) {
    const int h = bid >> 3, cq = bid & 7;
    __shared__ float qc_s[NB][HD];
    __shared__ float part_s[NB][256];
    for (int e = tid; e < NB*HD; e += 256) {
      int b = e >> 7, d = e & 127;
      float v = 0.f;
      #pragma unroll
      for (int p = 0; p < NP2; ++p)
        v += ws[WS_P2 + (size_t)(p*NB + b)*6144 + h*HD + d];
      qc_s[b][d] = v;
    }
    __syncthreads();
    const int c = cq*64 + (tid & 63);
    const int dg = tid >> 6;
    const float4* wrow = (const float4*)(Wuk + (size_t)c*(NH*HD) + h*HD + dg*32);
    float acc[NB] = {0,0,0,0};
    #pragma unroll
    for (int d4 = 0; d4 < 8; ++d4) {
      float4 w4 = wrow[d4];
      #pragma unroll
      for (int b = 0; b < NB; ++b)
        acc[b] += dot4(w4, *(const float4*)&qc_s[b][dg*32 + d4*4]);
    }
    #pragma unroll
    for (int b = 0; b < NB; ++b) part_s[b][tid] = acc[b];
    __syncthreads();
    if (tid < 64) {
      #pragma unroll
      for (int b = 0; b < NB; ++b) {
        float v = part_s[b][tid] + part_s[b][tid+64] + part_s[b][tid+128] + part_s[b][tid+192];
        ws[WS_QABS + (size_t)(b*NH + h)*CKV + cq*64 + tid] = v * SCALE_F;
      }
    }
  } else {
    const int b = bid - 256;
    const double LN1E4 = 9.210340371976184;
    for (int pid = tid; pid < NH*32; pid += 256) {
      int h = pid >> 5, i = pid & 31;
      float x1 = 0.f, x2 = 0.f;
      #pragma unroll
      for (int p = 0; p < NP2; ++p) {
        const float* base = ws + WS_P2 + (size_t)(p*NB + b)*6144 + 4096 + h*RD + 2*i;
        x1 += base[0]; x2 += base[1];
      }
      double ang = 4096.0 * exp(-(double)i / 32.0 * LN1E4);
      float cs = (float)cos(ang), sn = (float)sin(ang);
      ws[WS_QROPE + (b*NH + h)*RD + 2*i]     = (x1*cs - x2*sn) * SCALE_F;
      ws[WS_QROPE + (b*NH + h)*RD + 2*i + 1] = (x1*sn + x2*cs) * SCALE_F;
    }
  }
}

// ---------------- K4: scores v6 — reg-tiled 4h×2k, q from L2, NO fused copy -
// block: 64 keys × 32 heads × 144-dim c-quarter; grid (65, 4, 4) = 1040.
// Only kv in LDS (37.9 KB -> 4 blocks/CU); q broadcast-read from L2.
// LDS reads: 2 b128 per c4-iter per thread (72 total, vs 180 in R9).
__global__ __launch_bounds__(256)
void k_scores(const float* __restrict__ kv_cache,
              const float* __restrict__ kr_cache,
              float* __restrict__ ws) {
  __shared__ float4 kv_s[SC_T * SC_STR];
  const int tid = threadIdx.x;
  const int b  = blockIdx.z;
  const int cs = blockIdx.y;
  const int k0 = blockIdx.x * SC_T;
  // ---- stage kv tile (4 threads/row, 9 f4 each)
  {
    const int row = tid >> 2;
    const int c4a = (tid & 3) * 9;
    const int k = k0 + row;
    const int prow = ((row & 1) << 5) | (row >> 1);   // interleaved physical row
    const float4* kvr = nullptr; const float4* krr = nullptr;
    if (k < SS)       { kvr = (const float4*)(kv_cache + ((size_t)b*SS + k)*CKV);
                        krr = (const float4*)(kr_cache + ((size_t)b*SS + k)*RD); }
    else if (k == SS) { kvr = (const float4*)(ws + WS_CKV + b*CKV);
                        krr = (const float4*)(ws + WS_KROPE + b*RD); }
    #pragma unroll
    for (int i = 0; i < 9; ++i) {
      int c4 = c4a + i;
      int g4 = cs * SC_D4Q + c4;
      float4 v = make_float4(0.f, 0.f, 0.f, 0.f);
      if (kvr) v = (g4 < 128) ? kvr[g4] : krr[g4 - 128];
      kv_s[prow * SC_STR + c4] = v;
    }
  }
  __syncthreads();
  // ---- compute: thread = (hg=tid>>5 -> heads hg*4+i) × (kg=tid&31 -> keys 2kg+j)
  const int hg = tid >> 5, kg = tid & 31;
  const float4* qa[4]; const float4* qr[4];
  #pragma unroll
  for (int i = 0; i < 4; ++i) {
    int h = hg*4 + i;
    qa[i] = (const float4*)(ws + WS_QABS + (size_t)(b*NH + h)*CKV);
    qr[i] = (const float4*)(ws + WS_QROPE + (size_t)(b*NH + h)*RD);
  }
  const float4* kvrow0 = &kv_s[kg * SC_STR];           // logical row 2kg
  const float4* kvrow1 = &kv_s[(32 + kg) * SC_STR];    // logical row 2kg+1
  float acc[4][2] = {};
  if (cs < 3) {
    const int g0 = cs * SC_D4Q;
    #pragma unroll 4
    for (int c4 = 0; c4 < SC_D4Q; ++c4) {
      float4 kv0 = kvrow0[c4], kv1 = kvrow1[c4];
      #pragma unroll
      for (int i = 0; i < 4; ++i) {
        float4 q = qa[i][g0 + c4];
        acc[i][0] += dot4(q, kv0);
        acc[i][1] += dot4(q, kv1);
      }
    }
  } else {
    #pragma unroll 4
    for (int c4 = 0; c4 < 20; ++c4) {      // latent dims 432..511
      float4 kv0 = kvrow0[c4], kv1 = kvrow1[c4];
      #pragma unroll
      for (int i = 0; i < 4; ++i) {
        float4 q = qa[i][108 + c4];
        acc[i][0] += dot4(q, kv0);
        acc[i][1] += dot4(q, kv1);
      }
    }
    #pragma unroll 4
    for (int c4 = 20; c4 < 36; ++c4) {     // rope dims 0..63
      float4 kv0 = kvrow0[c4], kv1 = kvrow1[c4];
      #pragma unroll
      for (int i = 0; i < 4; ++i) {
        float4 q = qr[i][c4 - 20];
        acc[i][0] += dot4(q, kv0);
        acc[i][1] += dot4(q, kv1);
      }
    }
  }
  float* sbuf = ws + (cs == 0 ? WS_SCA : cs == 1 ? WS_SCB : cs == 2 ? WS_SCC : WS_SCD);
  const int ka = k0 + 2*kg, kb = ka + 1;
  #pragma unroll
  for (int i = 0; i < 4; ++i) {
    float* srow = sbuf + (size_t)(b*NH + hg*4 + i)*SKP;
    if (ka < SK) srow[ka] = acc[i][0];
    if (kb < SK) srow[kb] = acc[i][1];
  }
}

// ---------------- K5: softmax(SCA+SCB+SCC+SCD+mask) -> probs in SCA ---------
__global__ __launch_bounds__(256)
void k_softmax(const float* __restrict__ mask, float* __restrict__ ws) {
  __shared__ float red[256];
  const int tid = threadIdx.x;
  const int b = blockIdx.x >> 5;
  float* sa = ws + WS_SCA + (size_t)blockIdx.x * SKP;
  const float* sb = ws + WS_SCB + (size_t)blockIdx.x * SKP;
  const float* sc = ws + WS_SCC + (size_t)blockIdx.x * SKP;
  const float* sd = ws + WS_SCD + (size_t)blockIdx.x * SKP;
  const float* mrow = mask + (size_t)b * SK;
  float v[17];
  float m = -INFINITY;
  #pragma unroll
  for (int r = 0; r < 17; ++r) {
    int k = tid + r*256;
    v[r] = (k < SK) ? (sa[k] + sb[k] + sc[k] + sd[k] + mrow[k] * (-1e9f)) : -INFINITY;
    m = fmaxf(m, v[r]);
  }
  red[tid] = m; __syncthreads();
  for (int st = 128; st > 0; st >>= 1) {
    if (tid < st) red[tid] = fmaxf(red[tid], red[tid+st]);
    __syncthreads();
  }
  m = red[0]; __syncthreads();
  float e[17];
  float l = 0.f;
  #pragma unroll
  for (int r = 0; r < 17; ++r) {
    int k = tid + r*256;
    e[r] = (k < SK) ? __expf(v[r] - m) : 0.f;
    l += e[r];
  }
  red[tid] = l; __syncthreads();
  for (int st = 128; st > 0; st >>= 1) {
    if (tid < st) red[tid] += red[tid+st];
    __syncthreads();
  }
  float inv = 1.f / red[0];
  #pragma unroll
  for (int r = 0; r < 17; ++r) {
    int k = tid + r*256;
    if (k < SK) sa[k] = e[r] * inv;
  }
}

// ---------------- K6: o_latent partials — LDS-staged probs ------------------
__global__ __launch_bounds__(256)
void k_pv(const float* __restrict__ kv_cache, float* __restrict__ ws) {
  __shared__ float p_s[32][132];
  const int tid = threadIdx.x;
  const int c4 = tid & 15, hg = tid >> 4;
  const int b  = blockIdx.z;
  const int c  = blockIdx.y * 64 + c4 * 4;
  const int k0 = blockIdx.x * 128;
  #pragma unroll
  for (int j = 0; j < 4; ++j) {
    int e = tid + j*256;
    int h = e >> 5, k4 = e & 31;
    *(float4*)&p_s[h][k4*4] =
        *(const float4*)(ws + WS_SCA + (size_t)(b*NH + h)*SKP + k0 + k4*4);
  }
  __syncthreads();
  const float* kvp = kv_cache + ((size_t)b*SS + k0)*CKV + c;
  float4 acc0 = {}, acc1 = {};
  #pragma unroll 4
  for (int kk = 0; kk < 128; kk += 4) {
    float4 kv4[4];
    #pragma unroll
    for (int j = 0; j < 4; ++j)
      kv4[j] = *(const float4*)(kvp + (size_t)(kk + j)*CKV);
    float4 p4a = *(const float4*)&p_s[hg][kk];
    float4 p4b = *(const float4*)&p_s[hg + 16][kk];
    fma4(acc0, p4a.x, kv4[0]); fma4(acc1, p4b.x, kv4[0]);
    fma4(acc0, p4a.y, kv4[1]); fma4(acc1, p4b.y, kv4[1]);
    fma4(acc0, p4a.z, kv4[2]); fma4(acc1, p4b.z, kv4[2]);
    fma4(acc0, p4a.w, kv4[3]); fma4(acc1, p4b.w, kv4[3]);
  }
  if (blockIdx.x == NPV - 1) {
    float4 kv = *(const float4*)(ws + WS_CKV + b*CKV + c);
    float pa = ws[WS_SCA + (size_t)(b*NH + hg)*SKP + SS];
    float pb = ws[WS_SCA + (size_t)(b*NH + hg + 16)*SKP + SS];
    fma4(acc0, pa, kv);
    fma4(acc1, pb, kv);
  }
  *(float4*)(ws + WS_OPART + (((size_t)blockIdx.x*NB + b)*NH + hg)*CKV + c) = acc0;
  *(float4*)(ws + WS_OPART + (((size_t)blockIdx.x*NB + b)*NH + hg + 16)*CKV + c) = acc1;
}

// ---------------- R3: OLAT = sum_p OPART[p] ----------------------------------
__global__ __launch_bounds__(256)
void k_reduce3(float* __restrict__ ws) {
  const int idx = blockIdx.x * 256 + threadIdx.x;
  float4 s = {};
  #pragma unroll 8
  for (int p = 0; p < NPV; ++p) {
    float4 v = *(const float4*)(ws + WS_OPART + (size_t)p*(NB*NH*CKV) + (size_t)idx*4);
    s.x += v.x; s.y += v.y; s.z += v.z; s.w += v.w;
  }
  *(float4*)(ws + WS_OLAT + (size_t)idx*4) = s;
}

// ---------------- K7: UVPART = o_latent @ W_UV (block c-split) --------------
__global__ __launch_bounds__(256)
void k_uv(const float* __restrict__ Wuv, float* __restrict__ ws) {
  __shared__ float4 red_s[4][NB][64];
  const int lane = threadIdx.x & 63, csub = threadIdx.x >> 6;
  const int col4 = blockIdx.x * 64 + lane;
  const int h = col4 >> 5;
  const int k0 = blockIdx.y * 32 + csub * 8;
  const float4* wp = (const float4*)Wuv + (size_t)k0 * 1024 + col4;
  float4 acc[NB] = {};
  #pragma unroll
  for (int i = 0; i < 8; ++i) {
    float4 w4 = wp[(size_t)i * 1024];
    #pragma unroll
    for (int b = 0; b < NB; ++b)
      fma4(acc[b], ws[WS_OLAT + (size_t)(b*NH + h)*CKV + k0 + i], w4);
  }
  #pragma unroll
  for (int b = 0; b < NB; ++b) red_s[csub][b][lane] = acc[b];
  __syncthreads();
  if (csub == 0) {
    #pragma unroll
    for (int b = 0; b < NB; ++b) {
      float4 s = red_s[0][b][lane];
      #pragma unroll
      for (int j = 1; j < 4; ++j) {
        float4 v = red_s[j][b][lane];
        s.x += v.x; s.y += v.y; s.z += v.z; s.w += v.w;
      }
      *(float4*)(ws + WS_UVPART + (size_t)(blockIdx.y*NB + b)*HID + col4*4) = s;
    }
  }
}

// ---------------- R4: ATTN = sum_p UVPART[p] ---------------------------------
__global__ __launch_bounds__(256)
void k_reduce4(float* __restrict__ ws) {
  const int idx = blockIdx.x * 256 + threadIdx.x;
  float4 s = {};
  #pragma unroll
  for (int p = 0; p < NUV; ++p) {
    float4 v = *(const float4*)(ws + WS_UVPART + (size_t)p*(NB*HID) + (size_t)idx*4);
    s.x += v.x; s.y += v.y; s.z += v.z; s.w += v.w;
  }
  *(float4*)(ws + WS_ATTN + (size_t)idx*4) = s;
}

// ---------------- K8: WOPART = attn @ W_O (block k-split) --------------------
__global__ __launch_bounds__(256)
void k_wo(const float* __restrict__ Wo, const float* __restrict__ ws,
          float* __restrict__ wsp) {
  __shared__ float4 red_s[4][NB][64];
  const int lane = threadIdx.x & 63, ksub = threadIdx.x >> 6;
  const int col4 = blockIdx.x * 64 + lane;
  const int k0 = blockIdx.y * 128 + ksub * 32;
  const float4* wp = (const float4*)Wo + (size_t)k0 * 1024 + col4;
  float4 acc[NB] = {};
  #pragma unroll 8
  for (int i = 0; i < 32; ++i) {
    float4 w4 = wp[(size_t)i * 1024];
    #pragma unroll
    for (int b = 0; b < NB; ++b)
      fma4(acc[b], ws[WS_ATTN + b*HID + k0 + i], w4);
  }
  #pragma unroll
  for (int b = 0; b < NB; ++b) red_s[ksub][b][lane] = acc[b];
  __syncthreads();
  if (ksub == 0) {
    #pragma unroll
    for (int b = 0; b < NB; ++b) {
      float4 s = red_s[0][b][lane];
      #pragma unroll
      for (int j = 1; j < 4; ++j) {
        float4 v = red_s[j][b][lane];
        s.x += v.x; s.y += v.y; s.z += v.z; s.w += v.w;
      }
      *(float4*)(wsp + WS_WOPART + (size_t)(blockIdx.y*NB + b)*HID + col4*4) = s;
    }
  }
}

// ---------------- R5: out = sum_p WOPART[p] ----------------------------------
__global__ __launch_bounds__(256)
void k_reduce5(const float* __restrict__ ws, float* __restrict__ out) {
  const int idx = blockIdx.x * 256 + threadIdx.x;
  float4 s = {};
  #pragma unroll 8
  for (int p = 0; p < NWO; ++p) {
    float4 v = *(const float4*)(ws + WS_WOPART + (size_t)p*(NB*HID) + (size_t)idx*4);
    s.x += v.x; s.y += v.y; s.z += v.z; s.w += v.w;
  }
  *(float4*)(out + (size_t)idx*4) = s;
}

// ---------------- K9: cache copy (rows 0..4095), full-line writes ------------
__global__ __launch_bounds__(256)
void k_copy(const float4* __restrict__ src_ckv,
            const float4* __restrict__ src_kr,
            float4* __restrict__ dst_ckv,
            float4* __restrict__ dst_kr) {
  const int bx = blockIdx.x;
  if (bx < 8192) {
    int b = bx >> 11;
    int idx = (bx & 2047) * 256 + threadIdx.x;
    dst_ckv[(size_t)b*(SK*CKV/4) + idx] = src_ckv[(size_t)b*(SS*CKV/4) + idx];
  } else {
    int bx2 = bx - 8192;
    int b = bx2 >> 8;
    int idx = (bx2 & 255) * 256 + threadIdx.x;
    dst_kr[(size_t)b*(SK*RD/4) + idx] = src_kr[(size_t)b*(SS*RD/4) + idx];
  }
}

extern "C" void kernel_launch(void* const* d_in, const int* in_sizes, int n_in,
                              void* d_out, int out_size, void* d_ws, size_t ws_size,
                              hipStream_t stream) {
  (void)in_sizes; (void)n_in; (void)out_size; (void)ws_size;
  const float* hidden = (const float*)d_in[0];
  const float* mask   = (const float*)d_in[1];
  const float* ckv_c  = (const float*)d_in[2];
  const float* kr_c   = (const float*)d_in[3];
  const float* Wdkv   = (const float*)d_in[4];
  const float* Wuk    = (const float*)d_in[5];
  const float* Wuv    = (const float*)d_in[6];
  const float* Wdq    = (const float*)d_in[7];
  const float* Wuq    = (const float*)d_in[8];
  const float* Wqr    = (const float*)d_in[9];
  const float* Wkr    = (const float*)d_in[10];
  const float* Wo     = (const float*)d_in[11];
  float* out = (float*)d_out;
  float* ws  = (float*)d_ws;
  float* out_ckv = out + NB*HID;
  float* out_kr  = out + NB*HID + (size_t)NB*SK*CKV;

  k_copy<<<9216, 256, 0, stream>>>((const float4*)ckv_c, (const float4*)kr_c,
                                   (float4*)out_ckv, (float4*)out_kr);
  k_proj1<<<dim3(9, NP1), 256, 0, stream>>>(hidden, Wdkv, Wdq, Wkr, ws);
  k_reduce1<<<9, 256, 0, stream>>>(ws, out_ckv, out_kr);
  k_proj2<<<dim3(24, NP2), 256, 0, stream>>>(Wuq, Wqr, ws);
  k_absorb_rope<<<260, 256, 0, stream>>>(Wuk, ws);
  k_scores<<<dim3(65, 4, 4), 256, 0, stream>>>(ckv_c, kr_c, ws);
  k_softmax<<<NB*NH, 256, 0, stream>>>(mask, ws);
  k_pv<<<dim3(NPV, 8, 4), 256, 0, stream>>>(ckv_c, ws);
  k_reduce3<<<64, 256, 0, stream>>>(ws);
  k_uv<<<dim3(16, NUV), 256, 0, stream>>>(Wuv, ws);
  k_reduce4<<<16, 256, 0, stream>>>(ws);
  k_wo<<<dim3(16, NWO), 256, 0, stream>>>(Wo, ws, ws);
  k_reduce5<<<16, 256, 0, stream>>>(ws, out);
}

// Round 12
// 135.511 us; speedup vs baseline: 1.3611x; 1.1731x over previous
//
#include <hip/hip_runtime.h>
#include <math.h>

#define NB 4
#define HID 4096
#define CKV 512
#define CQ 1536
#define NH 32
#define HD 128
#define RD 64
#define SS 4096
#define SK 4097
#define SKP 4100  // padded scores row stride

#define SCALE_F 0.07216878364870322f  // 1/sqrt(192)

#define NP1 64   // proj1 k-partials
#define NP2 24   // proj2 k-partials
#define NPV 32   // pv key-chunks (128 keys)
#define NUV 16   // uv c-partials
#define NWO 32   // wo k-partials

#define SC_D4 36    // scores: 144 dims per c-quarter, in float4
#define SC_STR 148  // scores LDS row stride (floats)

// workspace offsets (floats). ALL regions disjoint (ws is 256 MB).
enum : int {
  WS_QABS  = 0,                        // [NB][NH][CKV] pre-scaled
  WS_QROPE = WS_QABS + NB*NH*CKV,      // [NB][NH][RD]  pre-scaled
  WS_KROPE = WS_QROPE + NB*NH*RD,      // [NB][RD]
  WS_CKV   = WS_KROPE + NB*RD,         // [NB][CKV]
  WS_CQ    = WS_CKV + NB*CKV,          // [NB][CQ] (written by reduce1; unused)
  WS_SCA   = WS_CQ + NB*CQ,            // [NB][NH][SKP] c-quarter 0 -> probs
  WS_SCB   = WS_SCA + NB*NH*SKP,
  WS_SCC   = WS_SCB + NB*NH*SKP,
  WS_SCD   = WS_SCC + NB*NH*SKP,
  WS_P1    = WS_SCD + NB*NH*SKP,       // [NP1][NB][528 f4] = 540672
  WS_P2    = WS_P1 + NP1*NB*528*4,     // [NP2][NB][6144]   = 589824
  WS_OPART = WS_P2 + NP2*NB*6144,      // [NPV][NB][NH][CKV]= 2097152
  WS_UVPART= WS_OPART + NPV*NB*NH*CKV, // [NUV][NB][HID]    = 262144
  WS_WOPART= WS_UVPART + NUV*NB*HID,   // [NWO][NB][HID]    = 524288
  WS_TOTAL = WS_WOPART + NWO*NB*HID    // ~6.3M floats = 25 MB
};

__device__ inline void fma4(float4& a, float s, const float4& v) {
  a.x += s*v.x; a.y += s*v.y; a.z += s*v.z; a.w += s*v.w;
}
__device__ inline float dot4(const float4& a, const float4& b) {
  return a.x*b.x + a.y*b.y + a.z*b.z + a.w*b.w;
}

// ------- L1: [bx<576] proj1 -> P1 partials | [else] cache copy --------------
__global__ __launch_bounds__(256)
void k_proj1copy(const float* __restrict__ hidden,
                 const float* __restrict__ Wdkv,
                 const float* __restrict__ Wdq,
                 const float* __restrict__ Wkr,
                 float* __restrict__ ws,
                 const float4* __restrict__ src_ckv,
                 const float4* __restrict__ src_kr,
                 float4* __restrict__ dst_ckv,
                 float4* __restrict__ dst_kr) {
  __shared__ float4 red_s[4][NB][64];
  const int bx = blockIdx.x;
  if (bx < 576) {
    const int gx = bx % 9, gy = bx / 9;      // col-tile, k-chunk
    const int lane = threadIdx.x & 63, ksub = threadIdx.x >> 6;
    const int col4 = gx * 64 + lane;
    const int k0 = gy * 64 + ksub * 16;
    const bool valid = col4 < 528;
    float4 acc[NB] = {};
    if (valid) {
      const float* W; int C4, wcol4;
      if (col4 < 128)      { W = Wdkv; C4 = 128; wcol4 = col4; }
      else if (col4 < 512) { W = Wdq;  C4 = 384; wcol4 = col4 - 128; }
      else                 { W = Wkr;  C4 = 16;  wcol4 = col4 - 512; }
      const float4* wp = (const float4*)W + (size_t)k0 * C4 + wcol4;
      #pragma unroll
      for (int i = 0; i < 16; ++i) {
        float4 w4 = wp[(size_t)i * C4];
        #pragma unroll
        for (int b = 0; b < NB; ++b) fma4(acc[b], hidden[b*HID + k0 + i], w4);
      }
    }
    #pragma unroll
    for (int b = 0; b < NB; ++b) red_s[ksub][b][lane] = acc[b];
    __syncthreads();
    if (ksub == 0 && valid) {
      #pragma unroll
      for (int b = 0; b < NB; ++b) {
        float4 s = red_s[0][b][lane];
        #pragma unroll
        for (int j = 1; j < 4; ++j) {
          float4 v = red_s[j][b][lane];
          s.x += v.x; s.y += v.y; s.z += v.z; s.w += v.w;
        }
        *(float4*)(ws + WS_P1 + ((size_t)(gy*NB + b)*528 + col4)*4) = s;
      }
    }
  } else {
    const int bxc = bx - 576;
    if (bxc < 8192) {
      int b = bxc >> 11;
      int idx = (bxc & 2047) * 256 + threadIdx.x;
      dst_ckv[(size_t)b*(SK*CKV/4) + idx] = src_ckv[(size_t)b*(SS*CKV/4) + idx];
    } else {
      int bx2 = bxc - 8192;
      int b = bx2 >> 8;
      int idx = (bx2 & 255) * 256 + threadIdx.x;
      dst_kr[(size_t)b*(SK*RD/4) + idx] = src_kr[(size_t)b*(SS*RD/4) + idx];
    }
  }
}

// ------- L2: [bx<576] proj2 (self-reduced act from P1) | [else] reduce1 ------
__global__ __launch_bounds__(256)
void k_proj2r1(const float* __restrict__ Wuq,
               const float* __restrict__ Wqr,
               float* __restrict__ ws,
               float* __restrict__ out_ckv,
               float* __restrict__ out_kr) {
  __shared__ float4 red_s[4][NB][64];
  __shared__ float act_s[NB][64];
  const int bx = blockIdx.x;
  const int tid = threadIdx.x;
  if (bx < 576) {
    const int gx = bx % 24, gy = bx / 24;    // col-tile, k-chunk (64 k)
    // pre-phase: act_s[b][i] = sum_p P1[p][b][CQ col (gy*64+i)]
    {
      const int b = tid >> 6, i = tid & 63;
      const int k = gy * 64 + i;
      const float* base = ws + WS_P1 + (size_t)b*2112 + 512 + k;  // (128*4 + k)
      float s = 0.f;
      #pragma unroll 8
      for (int p = 0; p < NP1; ++p) s += base[(size_t)p*NB*2112];
      act_s[b][i] = s;
    }
    __syncthreads();
    const int lane = tid & 63, ksub = tid >> 6;
    const int col4 = gx * 64 + lane;   // < 1536
    const float* W; int C4, wcol4;
    if (col4 < 1024) { W = Wuq; C4 = 1024; wcol4 = col4; }
    else             { W = Wqr; C4 = 512;  wcol4 = col4 - 1024; }
    const float4* wp = (const float4*)W + (size_t)(gy*64 + ksub*16) * C4 + wcol4;
    float4 acc[NB] = {};
    #pragma unroll
    for (int i = 0; i < 16; ++i) {
      float4 w4 = wp[(size_t)i * C4];
      #pragma unroll
      for (int b = 0; b < NB; ++b) fma4(acc[b], act_s[b][ksub*16 + i], w4);
    }
    #pragma unroll
    for (int b = 0; b < NB; ++b) red_s[ksub][b][lane] = acc[b];
    __syncthreads();
    if (ksub == 0) {
      #pragma unroll
      for (int b = 0; b < NB; ++b) {
        float4 s = red_s[0][b][lane];
        #pragma unroll
        for (int j = 1; j < 4; ++j) {
          float4 v = red_s[j][b][lane];
          s.x += v.x; s.y += v.y; s.z += v.z; s.w += v.w;
        }
        *(float4*)(ws + WS_P2 + (size_t)(gy*NB + b)*6144 + col4*4) = s;
      }
    }
  } else {
    // reduce1 branch: c_KV, k_R rope, new cache rows (9 blocks)
    const int w = (bx - 576) * 256 + tid;
    if (w >= 528*NB) return;
    const int b = w / 528, col4 = w % 528;
    float4 s = {};
    #pragma unroll 8
    for (int p = 0; p < NP1; ++p) {
      float4 v = *(const float4*)(ws + WS_P1 + ((size_t)(p*NB + b)*528 + col4)*4);
      s.x += v.x; s.y += v.y; s.z += v.z; s.w += v.w;
    }
    if (col4 < 128) {
      *(float4*)(ws + WS_CKV + b*CKV + col4*4) = s;
      *(float4*)(out_ckv + (size_t)b*SK*CKV + (size_t)SS*CKV + col4*4) = s;
    } else if (col4 < 512) {
      *(float4*)(ws + WS_CQ + b*CQ + (col4 - 128)*4) = s;
    } else {
      const int c0 = (col4 - 512) * 4;
      const double LN1E4 = 9.210340371976184;
      int i0 = c0 >> 1;
      double a0 = 4096.0 * exp(-(double)i0 / 32.0 * LN1E4);
      double a1 = 4096.0 * exp(-(double)(i0 + 1) / 32.0 * LN1E4);
      float c0f = (float)cos(a0), s0f = (float)sin(a0);
      float c1f = (float)cos(a1), s1f = (float)sin(a1);
      float4 o;
      o.x = s.x*c0f - s.y*s0f;  o.y = s.x*s0f + s.y*c0f;
      o.z = s.z*c1f - s.w*s1f;  o.w = s.z*s1f + s.w*c1f;
      *(float4*)(ws + WS_KROPE + b*RD + c0) = o;
      *(float4*)(out_kr + (size_t)b*SK*RD + (size_t)SS*RD + c0) = o;
    }
  }
}

// -------- L3: q_abs = q_C @ W_UK^T (×SCALE), P2-reduce fused; q_R RoPE -------
__global__ __launch_bounds__(256)
void k_absorb_rope(const float* __restrict__ Wuk,
                   float* __restrict__ ws) {
  const int bid = blockIdx.x, tid = threadIdx.x;
  if (bid < 256) {
    const int h = bid >> 3, cq = bid & 7;
    __shared__ float qc_s[NB][HD];
    __shared__ float part_s[NB][256];
    for (int e = tid; e < NB*HD; e += 256) {
      int b = e >> 7, d = e & 127;
      float v = 0.f;
      #pragma unroll
      for (int p = 0; p < NP2; ++p)
        v += ws[WS_P2 + (size_t)(p*NB + b)*6144 + h*HD + d];
      qc_s[b][d] = v;
    }
    __syncthreads();
    const int c = cq*64 + (tid & 63);
    const int dg = tid >> 6;
    const float4* wrow = (const float4*)(Wuk + (size_t)c*(NH*HD) + h*HD + dg*32);
    float acc[NB] = {0,0,0,0};
    #pragma unroll
    for (int d4 = 0; d4 < 8; ++d4) {
      float4 w4 = wrow[d4];
      #pragma unroll
      for (int b = 0; b < NB; ++b)
        acc[b] += dot4(w4, *(const float4*)&qc_s[b][dg*32 + d4*4]);
    }
    #pragma unroll
    for (int b = 0; b < NB; ++b) part_s[b][tid] = acc[b];
    __syncthreads();
    if (tid < 64) {
      #pragma unroll
      for (int b = 0; b < NB; ++b) {
        float v = part_s[b][tid] + part_s[b][tid+64] + part_s[b][tid+128] + part_s[b][tid+192];
        ws[WS_QABS + (size_t)(b*NH + h)*CKV + cq*64 + tid] = v * SCALE_F;
      }
    }
  } else {
    const int b = bid - 256;
    const double LN1E4 = 9.210340371976184;
    for (int pid = tid; pid < NH*32; pid += 256) {
      int h = pid >> 5, i = pid & 31;
      float x1 = 0.f, x2 = 0.f;
      #pragma unroll
      for (int p = 0; p < NP2; ++p) {
        const float* base = ws + WS_P2 + (size_t)(p*NB + b)*6144 + 4096 + h*RD + 2*i;
        x1 += base[0]; x2 += base[1];
      }
      double ang = 4096.0 * exp(-(double)i / 32.0 * LN1E4);
      float cs = (float)cos(ang), sn = (float)sin(ang);
      ws[WS_QROPE + (b*NH + h)*RD + 2*i]     = (x1*cs - x2*sn) * SCALE_F;
      ws[WS_QROPE + (b*NH + h)*RD + 2*i + 1] = (x1*sn + x2*cs) * SCALE_F;
    }
  }
}

// ---------------- L4: scores (R9 in-lane form) -------------------------------
// block: 32 heads × 32 keys × 144-dim c-quarter; grid (129, 4, 4) = 2064.
__global__ __launch_bounds__(256)
void k_scores(const float* __restrict__ kv_cache,
              const float* __restrict__ kr_cache,
              float* __restrict__ ws) {
  __shared__ float kv_s[32*SC_STR];
  __shared__ float q_s[32*SC_STR];
  const int tid = threadIdx.x;
  const int b  = blockIdx.z;
  const int cs = blockIdx.y;
  const int k0 = blockIdx.x * 32;
  const int r = tid >> 3, t7 = tid & 7;
  {
    const int k = k0 + r;
    const float4* kvr = (const float4*)(ws + WS_CKV);
    const float4* krr = (const float4*)(ws + WS_KROPE);
    const bool valid = (k <= SS);
    if (k < SS)       { kvr = (const float4*)(kv_cache + ((size_t)b*SS + k)*CKV);
                        krr = (const float4*)(kr_cache + ((size_t)b*SS + k)*RD); }
    else if (k == SS) { kvr = (const float4*)(ws + WS_CKV + b*CKV);
                        krr = (const float4*)(ws + WS_KROPE + b*RD); }
    #pragma unroll
    for (int i = 0; i < 5; ++i) {
      int c4 = t7 + 8*i;
      if (c4 < SC_D4) {
        int g4 = cs*SC_D4 + c4;
        float4 v = make_float4(0.f, 0.f, 0.f, 0.f);
        if (valid) v = (g4 < 128) ? kvr[g4] : krr[g4 - 128];
        *(float4*)&kv_s[r*SC_STR + c4*4] = v;
      }
    }
    const float4* qa = (const float4*)(ws + WS_QABS + (size_t)(b*NH + r)*CKV);
    const float4* qr = (const float4*)(ws + WS_QROPE + (size_t)(b*NH + r)*RD);
    #pragma unroll
    for (int i = 0; i < 5; ++i) {
      int c4 = t7 + 8*i;
      if (c4 < SC_D4) {
        int g4 = cs*SC_D4 + c4;
        float4 v = (g4 < 128) ? qa[g4] : qr[g4 - 128];
        *(float4*)&q_s[r*SC_STR + c4*4] = v;
      }
    }
  }
  __syncthreads();
  float acc[4] = {0.f, 0.f, 0.f, 0.f};
  const float* qrow = &q_s[r*SC_STR];
  #pragma unroll 4
  for (int c4 = 0; c4 < SC_D4; ++c4) {
    float4 q4 = *(const float4*)(qrow + c4*4);
    #pragma unroll
    for (int j = 0; j < 4; ++j) {
      float4 kv4 = *(const float4*)&kv_s[(t7 + 8*j)*SC_STR + c4*4];
      acc[j] += dot4(q4, kv4);
    }
  }
  float* sbuf = ws + (cs == 0 ? WS_SCA : cs == 1 ? WS_SCB : cs == 2 ? WS_SCC : WS_SCD);
  float* srow = sbuf + (size_t)(b*NH + r)*SKP;
  #pragma unroll
  for (int j = 0; j < 4; ++j) {
    int k = k0 + t7 + 8*j;
    if (k < SK) srow[k] = acc[j];
  }
}

// ---------------- L5: softmax(SCA+SCB+SCC+SCD+mask) -> probs in SCA ---------
__global__ __launch_bounds__(256)
void k_softmax(const float* __restrict__ mask, float* __restrict__ ws) {
  __shared__ float red[256];
  const int tid = threadIdx.x;
  const int b = blockIdx.x >> 5;
  float* sa = ws + WS_SCA + (size_t)blockIdx.x * SKP;
  const float* sb = ws + WS_SCB + (size_t)blockIdx.x * SKP;
  const float* sc = ws + WS_SCC + (size_t)blockIdx.x * SKP;
  const float* sd = ws + WS_SCD + (size_t)blockIdx.x * SKP;
  const float* mrow = mask + (size_t)b * SK;
  float v[17];
  float m = -INFINITY;
  #pragma unroll
  for (int r = 0; r < 17; ++r) {
    int k = tid + r*256;
    v[r] = (k < SK) ? (sa[k] + sb[k] + sc[k] + sd[k] + mrow[k] * (-1e9f)) : -INFINITY;
    m = fmaxf(m, v[r]);
  }
  red[tid] = m; __syncthreads();
  for (int st = 128; st > 0; st >>= 1) {
    if (tid < st) red[tid] = fmaxf(red[tid], red[tid+st]);
    __syncthreads();
  }
  m = red[0]; __syncthreads();
  float e[17];
  float l = 0.f;
  #pragma unroll
  for (int r = 0; r < 17; ++r) {
    int k = tid + r*256;
    e[r] = (k < SK) ? __expf(v[r] - m) : 0.f;
    l += e[r];
  }
  red[tid] = l; __syncthreads();
  for (int st = 128; st > 0; st >>= 1) {
    if (tid < st) red[tid] += red[tid+st];
    __syncthreads();
  }
  float inv = 1.f / red[0];
  #pragma unroll
  for (int r = 0; r < 17; ++r) {
    int k = tid + r*256;
    if (k < SK) sa[k] = e[r] * inv;
  }
}

// ---------------- L6: o_latent partials — LDS-staged probs ------------------
__global__ __launch_bounds__(256)
void k_pv(const float* __restrict__ kv_cache, float* __restrict__ ws) {
  __shared__ float p_s[32][132];
  const int tid = threadIdx.x;
  const int c4 = tid & 15, hg = tid >> 4;
  const int b  = blockIdx.z;
  const int c  = blockIdx.y * 64 + c4 * 4;
  const int k0 = blockIdx.x * 128;
  #pragma unroll
  for (int j = 0; j < 4; ++j) {
    int e = tid + j*256;
    int h = e >> 5, k4 = e & 31;
    *(float4*)&p_s[h][k4*4] =
        *(const float4*)(ws + WS_SCA + (size_t)(b*NH + h)*SKP + k0 + k4*4);
  }
  __syncthreads();
  const float* kvp = kv_cache + ((size_t)b*SS + k0)*CKV + c;
  float4 acc0 = {}, acc1 = {};
  #pragma unroll 4
  for (int kk = 0; kk < 128; kk += 4) {
    float4 kv4[4];
    #pragma unroll
    for (int j = 0; j < 4; ++j)
      kv4[j] = *(const float4*)(kvp + (size_t)(kk + j)*CKV);
    float4 p4a = *(const float4*)&p_s[hg][kk];
    float4 p4b = *(const float4*)&p_s[hg + 16][kk];
    fma4(acc0, p4a.x, kv4[0]); fma4(acc1, p4b.x, kv4[0]);
    fma4(acc0, p4a.y, kv4[1]); fma4(acc1, p4b.y, kv4[1]);
    fma4(acc0, p4a.z, kv4[2]); fma4(acc1, p4b.z, kv4[2]);
    fma4(acc0, p4a.w, kv4[3]); fma4(acc1, p4b.w, kv4[3]);
  }
  if (blockIdx.x == NPV - 1) {
    float4 kv = *(const float4*)(ws + WS_CKV + b*CKV + c);
    float pa = ws[WS_SCA + (size_t)(b*NH + hg)*SKP + SS];
    float pb = ws[WS_SCA + (size_t)(b*NH + hg + 16)*SKP + SS];
    fma4(acc0, pa, kv);
    fma4(acc1, pb, kv);
  }
  *(float4*)(ws + WS_OPART + (((size_t)blockIdx.x*NB + b)*NH + hg)*CKV + c) = acc0;
  *(float4*)(ws + WS_OPART + (((size_t)blockIdx.x*NB + b)*NH + hg + 16)*CKV + c) = acc1;
}

// ------- L7: uv with OPART self-reduce pre-phase (reduce3 folded in) --------
// grid 256: x = bx&15 (col-tile -> heads 2x,2x+1), y = bx>>4 (32-c range).
__global__ __launch_bounds__(256)
void k_uv2(const float* __restrict__ Wuv, float* __restrict__ ws) {
  __shared__ float4 red_s[4][NB][64];
  __shared__ float ol_s[NB][2][32];
  const int tid = threadIdx.x;
  const int x = blockIdx.x & 15, y = blockIdx.x >> 4;
  {
    const int b = tid >> 6, hh = (tid >> 5) & 1, ci = tid & 31;
    const float* base = ws + WS_OPART + ((size_t)b*NH + (2*x + hh))*CKV + y*32 + ci;
    float s = 0.f;
    #pragma unroll 8
    for (int p = 0; p < NPV; ++p) s += base[(size_t)p*(NB*NH*CKV)];
    ol_s[b][hh][ci] = s;
  }
  __syncthreads();
  const int lane = tid & 63, csub = tid >> 6;
  const int col4 = x * 64 + lane;
  const int hh = (col4 >> 5) & 1;
  const float4* wp = (const float4*)Wuv + (size_t)(y*32 + csub*8) * 1024 + col4;
  float4 acc[NB] = {};
  #pragma unroll
  for (int i = 0; i < 8; ++i) {
    float4 w4 = wp[(size_t)i * 1024];
    #pragma unroll
    for (int b = 0; b < NB; ++b)
      fma4(acc[b], ol_s[b][hh][csub*8 + i], w4);
  }
  #pragma unroll
  for (int b = 0; b < NB; ++b) red_s[csub][b][lane] = acc[b];
  __syncthreads();
  if (csub == 0) {
    #pragma unroll
    for (int b = 0; b < NB; ++b) {
      float4 s = red_s[0][b][lane];
      #pragma unroll
      for (int j = 1; j < 4; ++j) {
        float4 v = red_s[j][b][lane];
        s.x += v.x; s.y += v.y; s.z += v.z; s.w += v.w;
      }
      *(float4*)(ws + WS_UVPART + (size_t)(y*NB + b)*HID + col4*4) = s;
    }
  }
}

// ------- L8: wo with UVPART self-reduce pre-phase (reduce4 folded in) -------
// grid 512: x = bx&15 (col-tile), y = bx>>4 (128-k range).
__global__ __launch_bounds__(256)
void k_wo2(const float* __restrict__ Wo, float* __restrict__ ws) {
  __shared__ float4 red_s[4][NB][64];
  __shared__ float at_s[NB][128];
  const int tid = threadIdx.x;
  const int x = blockIdx.x & 15, y = blockIdx.x >> 4;
  {
    const int b = tid >> 6, q = tid & 63;
    #pragma unroll
    for (int e = 0; e < 2; ++e) {
      int idx = q*2 + e;
      const float* base = ws + WS_UVPART + (size_t)b*HID + y*128 + idx;
      float s = 0.f;
      #pragma unroll
      for (int p = 0; p < NUV; ++p) s += base[(size_t)p*(NB*HID)];
      at_s[b][idx] = s;
    }
  }
  __syncthreads();
  const int lane = tid & 63, ksub = tid >> 6;
  const int col4 = x * 64 + lane;
  const float4* wp = (const float4*)Wo + (size_t)(y*128 + ksub*32) * 1024 + col4;
  float4 acc[NB] = {};
  #pragma unroll 8
  for (int i = 0; i < 32; ++i) {
    float4 w4 = wp[(size_t)i * 1024];
    #pragma unroll
    for (int b = 0; b < NB; ++b)
      fma4(acc[b], at_s[b][ksub*32 + i], w4);
  }
  #pragma unroll
  for (int b = 0; b < NB; ++b) red_s[ksub][b][lane] = acc[b];
  __syncthreads();
  if (ksub == 0) {
    #pragma unroll
    for (int b = 0; b < NB; ++b) {
      float4 s = red_s[0][b][lane];
      #pragma unroll
      for (int j = 1; j < 4; ++j) {
        float4 v = red_s[j][b][lane];
        s.x += v.x; s.y += v.y; s.z += v.z; s.w += v.w;
      }
      *(float4*)(ws + WS_WOPART + (size_t)(y*NB + b)*HID + col4*4) = s;
    }
  }
}

// ---------------- L9: out = sum_p WOPART[p] ----------------------------------
__global__ __launch_bounds__(256)
void k_reduce5(const float* __restrict__ ws, float* __restrict__ out) {
  const int idx = blockIdx.x * 256 + threadIdx.x;
  float4 s = {};
  #pragma unroll 8
  for (int p = 0; p < NWO; ++p) {
    float4 v = *(const float4*)(ws + WS_WOPART + (size_t)p*(NB*HID) + (size_t)idx*4);
    s.x += v.x; s.y += v.y; s.z += v.z; s.w += v.w;
  }
  *(float4*)(out + (size_t)idx*4) = s;
}

extern "C" void kernel_launch(void* const* d_in, const int* in_sizes, int n_in,
                              void* d_out, int out_size, void* d_ws, size_t ws_size,
                              hipStream_t stream) {
  (void)in_sizes; (void)n_in; (void)out_size; (void)ws_size;
  const float* hidden = (const float*)d_in[0];
  const float* mask   = (const float*)d_in[1];
  const float* ckv_c  = (const float*)d_in[2];
  const float* kr_c   = (const float*)d_in[3];
  const float* Wdkv   = (const float*)d_in[4];
  const float* Wuk    = (const float*)d_in[5];
  const float* Wuv    = (const float*)d_in[6];
  const float* Wdq    = (const float*)d_in[7];
  const float* Wuq    = (const float*)d_in[8];
  const float* Wqr    = (const float*)d_in[9];
  const float* Wkr    = (const float*)d_in[10];
  const float* Wo     = (const float*)d_in[11];
  float* out = (float*)d_out;
  float* ws  = (float*)d_ws;
  float* out_ckv = out + NB*HID;
  float* out_kr  = out + NB*HID + (size_t)NB*SK*CKV;

  k_proj1copy<<<9792, 256, 0, stream>>>(hidden, Wdkv, Wdq, Wkr, ws,
                                        (const float4*)ckv_c, (const float4*)kr_c,
                                        (float4*)out_ckv, (float4*)out_kr);
  k_proj2r1<<<585, 256, 0, stream>>>(Wuq, Wqr, ws, out_ckv, out_kr);
  k_absorb_rope<<<260, 256, 0, stream>>>(Wuk, ws);
  k_scores<<<dim3(129, 4, 4), 256, 0, stream>>>(ckv_c, kr_c, ws);
  k_softmax<<<NB*NH, 256, 0, stream>>>(mask, ws);
  k_pv<<<dim3(NPV, 8, 4), 256, 0, stream>>>(ckv_c, ws);
  k_uv2<<<256, 256, 0, stream>>>(Wuv, ws);
  k_wo2<<<512, 256, 0, stream>>>(Wo, ws);
  k_reduce5<<<16, 256, 0, stream>>>(ws, out);
}